// Round 4
// baseline (7507.955 us; speedup 1.0000x reference)
//
#include <hip/hip_runtime.h>

#define N_PTS 65536
#define DIM   1024
#define NCLS  256
#define NITER 25

typedef __attribute__((ext_vector_type(8)))  short short8;
typedef __attribute__((ext_vector_type(16))) float f32x16;

// ---- RNE float -> bf16 split helper ------------------------------------------
__device__ __forceinline__ unsigned short bf_split(float x, float& rem) {
    unsigned u = __float_as_uint(x);
    unsigned b = (u + 0x7fffu + ((u >> 16) & 1u)) & 0xffff0000u;
    rem = x - __uint_as_float(b);
    return (unsigned short)(b >> 16);
}
__device__ __forceinline__ unsigned short bf_rne(float x) {
    unsigned u = __float_as_uint(x);
    return (unsigned short)((u + 0x7fffu + ((u >> 16) & 1u)) >> 16);
}

// ---------------- argmax(logits) -> init labels (first-max tie-break) ---------
__global__ void k_argmax(const float* __restrict__ logits, int* __restrict__ labels) {
    int row  = blockIdx.x * 4 + (threadIdx.x >> 6);
    int lane = threadIdx.x & 63;
    float4 v = reinterpret_cast<const float4*>(logits + (size_t)row * NCLS)[lane];
    float bv = v.x; int bi = lane * 4;
    if (v.y > bv) { bv = v.y; bi = lane * 4 + 1; }
    if (v.z > bv) { bv = v.z; bi = lane * 4 + 2; }
    if (v.w > bv) { bv = v.w; bi = lane * 4 + 3; }
    #pragma unroll
    for (int off = 32; off >= 1; off >>= 1) {
        float ov = __shfl_down(bv, off, 64);
        int   oi = __shfl_down(bi, off, 64);
        if (ov > bv || (ov == bv && oi < bi)) { bv = ov; bi = oi; }
    }
    if (lane == 0) labels[row] = bi;
}

// ---------------- label histogram (init only; steady-state fused in k_assign) --
__global__ void k_hist(const int* __restrict__ labels, int* __restrict__ counts) {
    __shared__ int h[NCLS];
    h[threadIdx.x] = 0;
    __syncthreads();
    for (int i = blockIdx.x * blockDim.x + threadIdx.x; i < N_PTS;
         i += gridDim.x * blockDim.x)
        atomicAdd(&h[labels[i]], 1);
    __syncthreads();
    int v = h[threadIdx.x];
    if (v) atomicAdd(&counts[threadIdx.x], v);
}

// ---------------- segment-sum accumulate (fixed-point, deterministic) ---------
// grid (32 dim-slices, 8 point-chunks of 8192), block 512, LDS 64 KB
__global__ __launch_bounds__(512) void k_accum(const float* __restrict__ feat,
                                               const int* __restrict__ labels,
                                               float* __restrict__ partials) {
    __shared__ unsigned long long s[NCLS * 32];
    int tid = threadIdx.x;
    for (int i = tid; i < NCLS * 32; i += 512) s[i] = 0ull;
    __syncthreads();
    int slice = blockIdx.x;
    int chunk = blockIdx.y;
    int w = tid >> 6, l = tid & 63;
    int sub = l >> 3;
    int dq  = l & 7;
    const size_t dbase = (size_t)slice * 32 + dq * 4;
    for (int step = 0; step < 128; ++step) {
        int p = chunk * 8192 + step * 64 + w * 8 + sub;
        int c = labels[p];
        float4 f = *reinterpret_cast<const float4*>(feat + (size_t)p * DIM + dbase);
        unsigned long long* dst = &s[c * 32 + dq * 4];
        atomicAdd(dst + 0, (unsigned long long)__double2ll_rn((double)f.x * 16777216.0));
        atomicAdd(dst + 1, (unsigned long long)__double2ll_rn((double)f.y * 16777216.0));
        atomicAdd(dst + 2, (unsigned long long)__double2ll_rn((double)f.z * 16777216.0));
        atomicAdd(dst + 3, (unsigned long long)__double2ll_rn((double)f.w * 16777216.0));
    }
    __syncthreads();
    float* out = partials + (size_t)chunk * NCLS * DIM;
    for (int i = tid; i < NCLS * 32; i += 512) {
        int c = i >> 5, d = i & 31;
        out[(size_t)c * DIM + slice * 32 + d] =
            (float)((double)(long long)s[i] * (1.0 / 16777216.0));
    }
}

// ---------------- fused finalize + norms + bf16x3 splitB ----------------------
// grid 256 (one block per class), block 256 (thread t owns dims 4t..4t+3).
// Per-thread mapping identical to the old k_finalize / k_norms -> bitwise-same.
__global__ void k_final(const float* __restrict__ partials,
                        const int* __restrict__ counts,
                        float* __restrict__ centroids,
                        float* __restrict__ norms,
                        unsigned short* __restrict__ Bs) {
    int c = blockIdx.x, t = threadIdx.x;
    size_t off = ((size_t)c * 256 + t) * 4;
    float4 sum = make_float4(0.f, 0.f, 0.f, 0.f);
    for (int ch = 0; ch < 8; ++ch) {
        float4 p = *reinterpret_cast<const float4*>(partials + (size_t)ch * NCLS * DIM + off);
        sum.x += p.x; sum.y += p.y; sum.z += p.z; sum.w += p.w;
    }
    int cnt = counts[c];
    float4 outv;
    if (cnt > 0) {
        float fc = (float)cnt;
        outv = make_float4(sum.x / fc, sum.y / fc, sum.z / fc, sum.w / fc);
    } else {
        outv = *reinterpret_cast<const float4*>(centroids + off);
    }
    *reinterpret_cast<float4*>(centroids + off) = outv;

    // ---- norms (verbatim old k_norms reduction; outv == centroids row)
    float s = outv.x * outv.x + outv.y * outv.y + outv.z * outv.z + outv.w * outv.w;
    __shared__ float red[4];
    #pragma unroll
    for (int o = 32; o >= 1; o >>= 1) s += __shfl_down(s, o, 64);
    if ((t & 63) == 0) red[t >> 6] = s;
    __syncthreads();
    if (t == 0) norms[c] = red[0] + red[1] + red[2] + red[3];

    // ---- bf16x3 split, MFMA-fragment-ordered (same values as old k_splitB)
    int k = t * 4;
    int kc = k >> 5, kh = (k >> 4) & 1, jg = (k >> 3) & 1, j0 = k & 7;  // j0 in {0,4}
    int nt = c >> 5, lane = (c & 31) + 32 * jg;
    float xv[4] = {outv.x, outv.y, outv.z, outv.w};
    unsigned short hv[4], mv[4], lv[4];
    #pragma unroll
    for (int e = 0; e < 4; ++e) {
        float r1, r2;
        hv[e] = bf_split(xv[e], r1);
        mv[e] = bf_split(r1, r2);
        lv[e] = bf_rne(r2);
    }
    #pragma unroll
    for (int p = 0; p < 3; ++p) {
        size_t base = ((((size_t)kc * 3 + p) * 8 + nt) * 2 + kh) * 512 + (size_t)lane * 8 + j0;
        const unsigned short* sp = (p == 0) ? hv : (p == 1) ? mv : lv;
        *reinterpret_cast<uint2*>(&Bs[base]) = *reinterpret_cast<const uint2*>(sp);
    }
}

// ---------------- assign: bf16x3 MFMA GEMM + fused argmin + fused hist --------
// block 256 (4 waves), tile M=128 (32 rows/wave) x N=256 (all classes).
// NO LDS staging, NO barriers in the K-loop: each wave reads its B fragments
// directly from L2-resident Bs (coalesced 16B/lane short8 loads) and free-runs.
// Waves on a SIMD drift out of phase so loads overlap MFMAs naturally.
// A is prefetched one kc ahead into the same registers (issued right after the
// split consumes them; lands under the ~3K-cycle MFMA phase).
// Per-accumulator MFMA order (q -> kh -> p) identical to the verified LDS
// version -> bitwise-identical labels.
__global__ __launch_bounds__(256, 2) void k_assign(
        const float* __restrict__ feat, const unsigned short* __restrict__ Bs,
        const float* __restrict__ norms, int* __restrict__ counts,
        int* __restrict__ out_labels) {
    __shared__ int h[NCLS];
    int tid = threadIdx.x, w = tid >> 6, l = tid & 63;
    int cn = l & 31, jg = l >> 5;
    int p0 = blockIdx.x * 128;
    h[tid] = 0;
    __syncthreads();   // hist zeroed before any wave reaches the epilogue

    f32x16 acc[8];
    #pragma unroll
    for (int t = 0; t < 8; ++t)
        #pragma unroll
        for (int i = 0; i < 16; ++i) acc[t][i] = 0.f;

    const float* arow = feat + (size_t)(p0 + w * 32 + cn) * DIM + jg * 8;

    float4 cur0 = *reinterpret_cast<const float4*>(arow);
    float4 cur1 = *reinterpret_cast<const float4*>(arow + 4);
    float4 cur2 = *reinterpret_cast<const float4*>(arow + 16);
    float4 cur3 = *reinterpret_cast<const float4*>(arow + 20);

    for (int kc = 0; kc < 32; ++kc) {
        // ---- split current A in-register -> fragments
        float xs[16] = {cur0.x, cur0.y, cur0.z, cur0.w, cur1.x, cur1.y, cur1.z, cur1.w,
                        cur2.x, cur2.y, cur2.z, cur2.w, cur3.x, cur3.y, cur3.z, cur3.w};
        union { short8 v; unsigned short u[8]; } af[2][3];
        #pragma unroll
        for (int kh = 0; kh < 2; ++kh)
            #pragma unroll
            for (int j = 0; j < 8; ++j) {
                float r1, r2;
                af[kh][0].u[j] = bf_split(xs[kh * 8 + j], r1);
                af[kh][1].u[j] = bf_split(r1, r2);
                af[kh][2].u[j] = bf_rne(r2);
            }
        // ---- prefetch next A (reuses the same registers; hidden under MFMAs)
        if (kc < 31) {
            const float* ab = arow + (kc + 1) * 32;
            cur0 = *reinterpret_cast<const float4*>(ab);
            cur1 = *reinterpret_cast<const float4*>(ab + 4);
            cur2 = *reinterpret_cast<const float4*>(ab + 16);
            cur3 = *reinterpret_cast<const float4*>(ab + 20);
        }
        // ---- B fragments direct from L2; 6 split-product pairings per kc
        const unsigned short* bkc = Bs + (size_t)kc * 24576 + (size_t)l * 8;
        #pragma unroll
        for (int q = 0; q < 3; ++q)
            #pragma unroll
            for (int kh = 0; kh < 2; ++kh) {
                short8 bf[8];
                #pragma unroll
                for (int ntl = 0; ntl < 8; ++ntl)
                    bf[ntl] = *reinterpret_cast<const short8*>(
                        bkc + ((q * 8 + ntl) * 2 + kh) * 512);
                const int np = (q == 0) ? 3 : (q == 1) ? 2 : 1;
                #pragma unroll
                for (int p = 0; p < 3; ++p)
                    if (p < np) {
                        #pragma unroll
                        for (int ntl = 0; ntl < 8; ++ntl)
                            acc[ntl] = __builtin_amdgcn_mfma_f32_32x32x16_bf16(
                                af[kh][p].v, bf[ntl], acc[ntl], 0, 0, 0);
                    }
            }
    }

    // epilogue: scores = ||mu||^2 - 2*dot ; argmin with first-index tie-break
    float nrm[8];
    #pragma unroll
    for (int ntl = 0; ntl < 8; ++ntl) nrm[ntl] = norms[ntl * 32 + cn];
    #pragma unroll
    for (int r = 0; r < 16; ++r) {
        unsigned long long key = ~0ull;
        #pragma unroll
        for (int ntl = 0; ntl < 8; ++ntl) {
            float s = nrm[ntl] - 2.0f * acc[ntl][r];
            unsigned u = __float_as_uint(s);
            u = (u & 0x80000000u) ? ~u : (u | 0x80000000u);
            unsigned long long kk =
                ((unsigned long long)u << 32) | (unsigned)(ntl * 32 + cn);
            key = (kk < key) ? kk : key;
        }
        #pragma unroll
        for (int off = 16; off >= 1; off >>= 1) {
            unsigned long long ok = __shfl_xor(key, off, 64);
            key = (ok < key) ? ok : key;
        }
        if (cn == 0) {
            int m = p0 + w * 32 + (r & 3) + 8 * (r >> 2) + 4 * jg;
            int lab = (int)(key & 0xffffffffull);
            out_labels[m] = lab;
            atomicAdd(&h[lab], 1);
        }
    }
    __syncthreads();
    int v = h[tid];
    if (v) atomicAdd(&counts[tid], v);
}

// ---------------- driver -------------------------------------------------------
extern "C" void kernel_launch(void* const* d_in, const int* in_sizes, int n_in,
                              void* d_out, int out_size, void* d_ws, size_t ws_size,
                              hipStream_t stream) {
    const float* feat   = (const float*)d_in[0];
    const float* logits = (const float*)d_in[1];
    int* out_labels = (int*)d_out;

    char* ws = (char*)d_ws;
    float* centroids            = (float*)ws;                        // 1 MB
    float* partials             = (float*)(ws + 0x100000);           // 8 MB
    float* norms                = (float*)(ws + 0x900000);           // 1 KB
    int*   counts               = (int*)  (ws + 0x901000);           // 1 KB
    int*   labels               = (int*)  (ws + 0x902000);           // 256 KB
    unsigned short* Bs          = (unsigned short*)(ws + 0x950000);  // 1.5 MB

    // ---- init: labels from argmax(logits); centroids from label centers
    k_argmax<<<N_PTS / 4, 256, 0, stream>>>(logits, labels);
    hipMemsetAsync(centroids, 0, (size_t)NCLS * DIM * sizeof(float), stream);
    hipMemsetAsync(counts, 0, NCLS * sizeof(int), stream);
    k_hist<<<64, 256, 0, stream>>>(labels, counts);
    k_accum<<<dim3(32, 8), 512, 0, stream>>>(feat, labels, partials);
    k_final<<<NCLS, 256, 0, stream>>>(partials, counts, centroids, norms, Bs);

    // ---- 25 Lloyd iterations (assign fuses hist; k_final fuses norms+splitB)
    for (int it = 0; it < NITER; ++it) {
        hipMemsetAsync(counts, 0, NCLS * sizeof(int), stream);
        k_assign<<<N_PTS / 128, 256, 0, stream>>>(feat, Bs, norms, counts, labels);
        k_accum<<<dim3(32, 8), 512, 0, stream>>>(feat, labels, partials);
        k_final<<<NCLS, 256, 0, stream>>>(partials, counts, centroids, norms, Bs);
    }

    // ---- final assignment -> output labels (counts write is harmless garbage)
    k_assign<<<N_PTS / 128, 256, 0, stream>>>(feat, Bs, norms, counts, out_labels);
}